// Round 3
// baseline (137.325 us; speedup 1.0000x reference)
//
#include <hip/hip_runtime.h>
#include <math.h>

#define NXD 128
#define NHD 256
#define NUD 16
#define NPIC 6           // Picard iterations per implicit stage (contraction ~0.011/iter)
#define HSTEP 0.02f
#define GAMMA_ 0.26f
#define LEAK_ 0.1f

// Kvaerno(5) ESDIRK tableau (lower rows, diagonal = GAMMA)
__device__ __constant__ float c_A[6][6] = {
  {0.26f, 0.f, 0.f, 0.f, 0.f, 0.f},
  {0.13f, 0.84033320996790809f, 0.f, 0.f, 0.f, 0.f},
  {0.22371961478320505f, 0.47675532319799699f, -0.06470895363112615f, 0.f, 0.f, 0.f},
  {0.16648564323248321f, 0.1045001884159172f, 0.03631482272098715f, -0.13090704451073998f, 0.f, 0.f},
  {0.13855640231268224f, 0.f, -0.04245337201752043f, 0.02446657898003141f, 0.61943039072480676f, 0.f},
  {0.13659751177640291f, 0.f, -0.05496908796538376f, -0.04118626728321046f, 0.62993304899016403f, 0.06962479448202728f},
};
__device__ __constant__ float c_B[7] = {
  0.13659751177640291f, 0.f, -0.05496908796538376f, -0.04118626728321046f,
  0.62993304899016403f, 0.06962479448202728f, 0.26f
};

// One workgroup per batch element. 512 threads:
//   W1 (256x128): thread t -> row r1=t>>1, col-half c1=t&1, holds 64 fp32 in regs
//   W2 (128x256): thread t -> row r2=t>>2, quarter  q2=t&3, holds 64 fp32 in regs
// Partial dots combined via in-wave shfl_xor (1) / (1,2).
__global__ __launch_bounds__(512, 2)
void kv5_kernel(const float* __restrict__ x, const float* __restrict__ u,
                const float* __restrict__ W1g, const float* __restrict__ b1,
                const float* __restrict__ Bug, const float* __restrict__ W2g,
                const float* __restrict__ b2, float* __restrict__ out)
{
  const int bidx = blockIdx.x;
  const int t = threadIdx.x;
  const int r1 = t >> 1, c1 = t & 1;
  const int r2 = t >> 2, q2 = t & 3;

  __shared__ __align__(16) float s_y[NXD];
  __shared__ __align__(16) float s_pred[NXD];
  __shared__ __align__(16) float s_y0[NXD];
  __shared__ __align__(16) float s_k[7][NXD];
  __shared__ __align__(16) float s_cu[NHD];
  __shared__ __align__(16) float s_hid[NHD];
  __shared__ __align__(16) float s_b2[NXD];
  __shared__ __align__(16) float s_u[NUD];

  // ---- one-time: weights into registers (stay resident for all 37 f-evals) ----
  float w1r[64], w2r[64];
  {
    const float* p1 = W1g + (size_t)r1 * NXD + c1 * 64;
    const float* p2 = W2g + (size_t)r2 * NHD + q2 * 64;
    #pragma unroll
    for (int j = 0; j < 64; j += 4) {
      *reinterpret_cast<float4*>(&w1r[j]) = *reinterpret_cast<const float4*>(&p1[j]);
      *reinterpret_cast<float4*>(&w2r[j]) = *reinterpret_cast<const float4*>(&p2[j]);
    }
  }
  if (t < NXD) { s_y0[t] = x[bidx * NXD + t]; s_b2[t] = b2[t]; }
  if (t < NUD) { float uv = u[bidx * NUD + t]; s_u[t] = fminf(fmaxf(uv, -1.f), 1.f); }
  __syncthreads();
  if (t < NHD) {                       // cu = Bu @ clip(u) + b1 (constant for the step)
    float a = b1[t];
    #pragma unroll
    for (int j = 0; j < NUD; ++j) a = fmaf(Bug[t * NUD + j], s_u[j], a);
    s_cu[t] = a;
  }

  // f(y) = -leak*y + W2 @ tanh(W1 @ y + cu) + b2 ; y in s_y, result -> kout
  auto feval = [&](float* kout) {
    float acc = 0.f;
    const float* yh = s_y + c1 * 64;
    #pragma unroll
    for (int j = 0; j < 64; j += 4) {
      float4 v = *reinterpret_cast<const float4*>(&yh[j]);   // LDS b128, broadcast
      acc = fmaf(w1r[j],   v.x, acc);
      acc = fmaf(w1r[j+1], v.y, acc);
      acc = fmaf(w1r[j+2], v.z, acc);
      acc = fmaf(w1r[j+3], v.w, acc);
    }
    acc += __shfl_xor(acc, 1);
    if (c1 == 0) s_hid[r1] = tanhf(acc + s_cu[r1]);
    __syncthreads();
    float a2 = 0.f;
    const float* hh = s_hid + q2 * 64;
    #pragma unroll
    for (int j = 0; j < 64; j += 4) {
      float4 v = *reinterpret_cast<const float4*>(&hh[j]);
      a2 = fmaf(w2r[j],   v.x, a2);
      a2 = fmaf(w2r[j+1], v.y, a2);
      a2 = fmaf(w2r[j+2], v.z, a2);
      a2 = fmaf(w2r[j+3], v.w, a2);
    }
    a2 += __shfl_xor(a2, 1);
    a2 += __shfl_xor(a2, 2);
    if (q2 == 0) kout[r2] = fmaf(-LEAK_, s_y[r2], a2 + s_b2[r2]);
    __syncthreads();
  };

  // ---- stage 1 (explicit): k0 = f(y0) ----
  if (t < NXD) s_y[t] = s_y0[t];
  __syncthreads();                    // also covers s_cu
  feval(s_k[0]);

  // ---- stages 2..7: fixed-point solve k = f(pred + h*gamma*k) ----
  for (int s = 1; s < 7; ++s) {
    if (t < NXD) {
      float p = s_y0[t];
      for (int j = 0; j < s; ++j) p = fmaf(HSTEP * c_A[s-1][j], s_k[j][t], p);
      s_pred[t] = p;
      s_k[s][t] = s_k[s-1][t];        // warm start = previous stage k (matches ref)
    }
    __syncthreads();
    #pragma unroll 1
    for (int it = 0; it < NPIC; ++it) {
      if (t < NXD) s_y[t] = fmaf(HSTEP * GAMMA_, s_k[s][t], s_pred[t]);
      __syncthreads();
      feval(s_k[s]);
    }
  }

  // ---- y1 = y0 + h * sum b_j k_j ----
  if (t < NXD) {
    float yv = s_y0[t];
    #pragma unroll
    for (int j = 0; j < 7; ++j) yv = fmaf(HSTEP * c_B[j], s_k[j][t], yv);
    out[bidx * NXD + t] = yv;
  }
}

extern "C" void kernel_launch(void* const* d_in, const int* in_sizes, int n_in,
                              void* d_out, int out_size, void* d_ws, size_t ws_size,
                              hipStream_t stream) {
  const float* x  = (const float*)d_in[0];
  const float* u  = (const float*)d_in[1];
  const float* W1 = (const float*)d_in[2];
  const float* b1 = (const float*)d_in[3];
  const float* Bu = (const float*)d_in[4];
  const float* W2 = (const float*)d_in[5];
  const float* b2 = (const float*)d_in[6];
  float* out = (float*)d_out;
  const int B = in_sizes[0] / NXD;
  hipLaunchKernelGGL(kv5_kernel, dim3(B), dim3(512), 0, stream,
                     x, u, W1, b1, Bu, W2, b2, out);
}

// Round 8
// 103.962 us; speedup vs baseline: 1.3209x; 1.3209x over previous
//
#include <hip/hip_runtime.h>
#include <math.h>

#define NXD 128
#define NHD 256
#define NUD 16
#define NPIC 4           // Picard iters/stage: contraction ~0.011/iter, warm-start err ~0.13 -> ~2e-9
#define HSTEP 0.02f
#define GAMMA_ 0.26f
#define LEAK_ 0.1f

// Kvaerno(5) ESDIRK tableau (lower rows, diagonal = GAMMA)
__device__ __constant__ float c_A[6][6] = {
  {0.26f, 0.f, 0.f, 0.f, 0.f, 0.f},
  {0.13f, 0.84033320996790809f, 0.f, 0.f, 0.f, 0.f},
  {0.22371961478320505f, 0.47675532319799699f, -0.06470895363112615f, 0.f, 0.f, 0.f},
  {0.16648564323248321f, 0.1045001884159172f, 0.03631482272098715f, -0.13090704451073998f, 0.f, 0.f},
  {0.13855640231268224f, 0.f, -0.04245337201752043f, 0.02446657898003141f, 0.61943039072480676f, 0.f},
  {0.13659751177640291f, 0.f, -0.05496908796538376f, -0.04118626728321046f, 0.62993304899016403f, 0.06962479448202728f},
};
__device__ __constant__ float c_B[7] = {
  0.13659751177640291f, 0.f, -0.05496908796538376f, -0.04118626728321046f,
  0.62993304899016403f, 0.06962479448202728f, 0.26f
};

// One workgroup per batch element. 512 threads:
//   W1 (256x128): thread t -> row r1=t>>1, col-half c1=t&1, 64 fp32 in regs
//   W2 (128x256): thread t -> row r2=t>>2, quarter  q2=t&3, 64 fp32 in regs,
//                 stored ROTATED by 16*q2 within the quarter (LDS bank spread)
// Weights are PINNED in VGPRs via opaque asm so the compiler cannot
// rematerialize the global loads inside the 25-eval loop (round-3 post-mortem:
// VGPR=88 proved rematerialization -> 2.4 GB L2 re-reads -> 78us).
__global__ __launch_bounds__(512, 2)
void kv5_kernel(const float* __restrict__ x, const float* __restrict__ u,
                const float* __restrict__ W1g, const float* __restrict__ b1,
                const float* __restrict__ Bug, const float* __restrict__ W2g,
                const float* __restrict__ b2, float* __restrict__ out)
{
  const int bidx = blockIdx.x;
  const int t = threadIdx.x;
  const int r1 = t >> 1, c1 = t & 1;
  const int r2 = t >> 2, q2 = t & 3;
  const int rot = (q2 << 4);           // rotation start within W2 quarter

  __shared__ __align__(16) float s_y[NXD];
  __shared__ __align__(16) float s_pred[NXD];
  __shared__ __align__(16) float s_y0[NXD];
  __shared__ __align__(16) float s_k[7][NXD];
  __shared__ __align__(16) float s_cu[NHD];
  __shared__ __align__(16) float s_hid[NHD];
  __shared__ __align__(16) float s_b2[NXD];
  __shared__ __align__(16) float s_u[NUD];

  // ---- one-time: weights into registers, then pin ----
  float w1r[64], w2r[64];
  {
    const float* p1 = W1g + (size_t)r1 * NXD + c1 * 64;
    const float* p2 = W2g + (size_t)r2 * NHD + (q2 << 6);
    #pragma unroll
    for (int j = 0; j < 64; j += 4) {
      *reinterpret_cast<float4*>(&w1r[j]) = *reinterpret_cast<const float4*>(&p1[j]);
      int jr = (rot + j) & 63;         // rotated load so dot indices line up
      *reinterpret_cast<float4*>(&w2r[j]) = *reinterpret_cast<const float4*>(&p2[jr]);
    }
    #pragma unroll
    for (int j = 0; j < 64; ++j) {
      asm volatile("" : "+v"(w1r[j]));
      asm volatile("" : "+v"(w2r[j]));
    }
  }
  if (t < NXD) { s_y0[t] = x[bidx * NXD + t]; s_b2[t] = b2[t]; }
  if (t < NUD) { float uv = u[bidx * NUD + t]; s_u[t] = fminf(fmaxf(uv, -1.f), 1.f); }
  __syncthreads();
  if (t < NHD) {                       // cu = Bu @ clip(u) + b1 (constant for the step)
    float a = b1[t];
    #pragma unroll
    for (int j = 0; j < NUD; ++j) a = fmaf(Bug[t * NUD + j], s_u[j], a);
    s_cu[t] = a;
  }

  // f(y): y in s_y -> k in kout. If WY, owner thread also writes
  // s_y[r2] = s_pred[r2] + h*gamma*k_new for the next Picard iteration.
  auto feval = [&](float* kout, bool wy) {
    float acc = 0.f;
    const float* yh = s_y + (c1 << 6);
    #pragma unroll
    for (int j = 0; j < 64; j += 4) {
      float4 v = *reinterpret_cast<const float4*>(&yh[j]);   // 2 uniq addrs, 2-way free
      acc = fmaf(w1r[j],   v.x, acc);
      acc = fmaf(w1r[j+1], v.y, acc);
      acc = fmaf(w1r[j+2], v.z, acc);
      acc = fmaf(w1r[j+3], v.w, acc);
    }
    acc += __shfl_xor(acc, 1);
    if (c1 == 0) s_hid[r1] = tanhf(acc + s_cu[r1]);
    __syncthreads();
    float a2 = 0.f;
    const float* hh = s_hid + (q2 << 6);
    #pragma unroll
    for (int j = 0; j < 64; j += 4) {
      int jr = (rot + j) & 63;         // rotated: banks {0,16,0,16} across q2
      float4 v = *reinterpret_cast<const float4*>(&hh[jr]);
      a2 = fmaf(w2r[j],   v.x, a2);
      a2 = fmaf(w2r[j+1], v.y, a2);
      a2 = fmaf(w2r[j+2], v.z, a2);
      a2 = fmaf(w2r[j+3], v.w, a2);
    }
    a2 += __shfl_xor(a2, 1);
    a2 += __shfl_xor(a2, 2);
    if (q2 == 0) {
      float knew = fmaf(-LEAK_, s_y[r2], a2 + s_b2[r2]);
      kout[r2] = knew;
      if (wy) s_y[r2] = fmaf(HSTEP * GAMMA_, knew, s_pred[r2]);
    }
    __syncthreads();
  };

  // ---- stage 1 (explicit): k0 = f(y0) ----
  if (t < NXD) s_y[t] = s_y0[t];
  __syncthreads();                    // also covers s_cu
  feval(s_k[0], false);

  // ---- stages 2..7: fixed-point solve k = f(pred + h*gamma*k) ----
  for (int s = 1; s < 7; ++s) {
    if (t < NXD) {
      float p = s_y0[t];
      for (int j = 0; j < s; ++j) p = fmaf(HSTEP * c_A[s-1][j], s_k[j][t], p);
      s_pred[t] = p;
      // warm start y = pred + h*gamma*k_{s-1}
      s_y[t] = fmaf(HSTEP * GAMMA_, s_k[s-1][t], p);
    }
    __syncthreads();
    #pragma unroll 1
    for (int it = 0; it < NPIC; ++it)
      feval(s_k[s], it != NPIC - 1);
  }

  // ---- y1 = y0 + h * sum b_j k_j ----
  if (t < NXD) {
    float yv = s_y0[t];
    #pragma unroll
    for (int j = 0; j < 7; ++j) yv = fmaf(HSTEP * c_B[j], s_k[j][t], yv);
    out[bidx * NXD + t] = yv;
  }
}

extern "C" void kernel_launch(void* const* d_in, const int* in_sizes, int n_in,
                              void* d_out, int out_size, void* d_ws, size_t ws_size,
                              hipStream_t stream) {
  const float* x  = (const float*)d_in[0];
  const float* u  = (const float*)d_in[1];
  const float* W1 = (const float*)d_in[2];
  const float* b1 = (const float*)d_in[3];
  const float* Bu = (const float*)d_in[4];
  const float* W2 = (const float*)d_in[5];
  const float* b2 = (const float*)d_in[6];
  float* out = (float*)d_out;
  const int B = in_sizes[0] / NXD;
  hipLaunchKernelGGL(kv5_kernel, dim3(B), dim3(512), 0, stream,
                     x, u, W1, b1, Bu, W2, b2, out);
}

// Round 10
// 93.606 us; speedup vs baseline: 1.4671x; 1.1106x over previous
//
#include <hip/hip_runtime.h>
#include <math.h>

#define NXD 128
#define NHD 256
#define NUD 16
#define NPIC 2           // Picard iters/stage: rho~0.011, warm-start err<~0.3 -> k-err ~4e-5
#define HSTEP 0.02f
#define GAMMA_ 0.26f
#define LEAK_ 0.1f

// Kvaerno(5) ESDIRK tableau (lower rows, diagonal = GAMMA)
__device__ __constant__ float c_A[6][6] = {
  {0.26f, 0.f, 0.f, 0.f, 0.f, 0.f},
  {0.13f, 0.84033320996790809f, 0.f, 0.f, 0.f, 0.f},
  {0.22371961478320505f, 0.47675532319799699f, -0.06470895363112615f, 0.f, 0.f, 0.f},
  {0.16648564323248321f, 0.1045001884159172f, 0.03631482272098715f, -0.13090704451073998f, 0.f, 0.f},
  {0.13855640231268224f, 0.f, -0.04245337201752043f, 0.02446657898003141f, 0.61943039072480676f, 0.f},
  {0.13659751177640291f, 0.f, -0.05496908796538376f, -0.04118626728321046f, 0.62993304899016403f, 0.06962479448202728f},
};
__device__ __constant__ float c_B7[7] = {
  0.13659751177640291f, 0.f, -0.05496908796538376f, -0.04118626728321046f,
  0.62993304899016403f, 0.06962479448202728f, 0.26f
};

// One workgroup (1024 thr) per batch element.
//   W1 (256x128): thread t -> row r1=t>>2, col-block c1=t&3 (32 cols), 8 float4 regs
//   W2 (128x256): thread t -> row r2=t>>3, col-block q2=t&7 (32 cols), 8 float4 regs
// 64 weight VGPRs + ~35 working < 128-VGPR tier; amdgpu_waves_per_eu(4,4) pins
// the scheduler's occupancy target to that tier so it has NO incentive to
// rematerialize the weight loads into the eval loop (rounds 3/8 post-mortem:
// VGPR=88/92 + 38 TB/s L2 traffic proved remat; L2-BW-bound at 44us).
// Rotations make all LDS activation reads bank-conflict-free:
//   W1: bank(c1,j) = (8*c1 + 4j..)&31 -> 4 disjoint quads
//   W2: bank(q2,j) = 4*((q2+j)&7)     -> 8 disjoint quads
__global__ __launch_bounds__(1024) __attribute__((amdgpu_waves_per_eu(4, 4)))
void kv5_kernel(const float* __restrict__ x, const float* __restrict__ u,
                const float* __restrict__ W1g, const float* __restrict__ b1,
                const float* __restrict__ Bug, const float* __restrict__ W2g,
                const float* __restrict__ b2, float* __restrict__ out)
{
  const int bidx = blockIdx.x;
  const int t = threadIdx.x;
  const int r1 = t >> 2, c1 = t & 3;
  const int r2 = t >> 3, q2 = t & 7;

  __shared__ __align__(16) float s_y[NXD];
  __shared__ __align__(16) float s_pred[NXD];
  __shared__ __align__(16) float s_y0[NXD];
  __shared__ __align__(16) float s_k[7][NXD];
  __shared__ __align__(16) float s_cu[NHD];
  __shared__ __align__(16) float s_hid[NHD];
  __shared__ __align__(16) float s_b2[NXD];
  __shared__ __align__(16) float s_u[NUD];

  // ---- one-time: weights into registers (rotated), then pin ----
  float4 w1q[8], w2q[8];
  {
    const float4* p1 = reinterpret_cast<const float4*>(W1g + (size_t)r1 * NXD + (c1 << 5));
    const float4* p2 = reinterpret_cast<const float4*>(W2g + (size_t)r2 * NHD + (q2 << 5));
    #pragma unroll
    for (int j = 0; j < 8; ++j) {
      w1q[j] = p1[((c1 << 1) + j) & 7];
      w2q[j] = p2[(q2 + j) & 7];
    }
    #pragma unroll
    for (int j = 0; j < 8; ++j) {
      asm volatile("" : "+v"(w1q[j].x), "+v"(w1q[j].y), "+v"(w1q[j].z), "+v"(w1q[j].w));
      asm volatile("" : "+v"(w2q[j].x), "+v"(w2q[j].y), "+v"(w2q[j].z), "+v"(w2q[j].w));
    }
  }
  if (t < NXD) { s_y0[t] = x[bidx * NXD + t]; s_b2[t] = b2[t]; }
  if (t < NUD) { float uv = u[bidx * NUD + t]; s_u[t] = fminf(fmaxf(uv, -1.f), 1.f); }
  __syncthreads();
  if (t < NHD) {                       // cu = Bu @ clip(u) + b1 (constant for the step)
    float a = b1[t];
    #pragma unroll
    for (int j = 0; j < NUD; ++j) a = fmaf(Bug[t * NUD + j], s_u[j], a);
    s_cu[t] = a;
  }

  // f(y): y in s_y -> k in kout. If WY, owner thread also writes
  // s_y[r2] = s_pred[r2] + h*gamma*k_new for the next Picard iteration.
  auto feval = [&](float* kout, bool wy) {
    const float4* y4 = reinterpret_cast<const float4*>(s_y + (c1 << 5));
    float acc = 0.f;
    #pragma unroll
    for (int j = 0; j < 8; ++j) {
      float4 v = y4[((c1 << 1) + j) & 7];   // rotated: conflict-free
      acc = fmaf(w1q[j].x, v.x, acc);
      acc = fmaf(w1q[j].y, v.y, acc);
      acc = fmaf(w1q[j].z, v.z, acc);
      acc = fmaf(w1q[j].w, v.w, acc);
    }
    acc += __shfl_xor(acc, 1);
    acc += __shfl_xor(acc, 2);
    if (c1 == 0) s_hid[r1] = tanhf(acc + s_cu[r1]);
    __syncthreads();
    const float4* h4 = reinterpret_cast<const float4*>(s_hid + (q2 << 5));
    float a2 = 0.f;
    #pragma unroll
    for (int j = 0; j < 8; ++j) {
      float4 v = h4[(q2 + j) & 7];          // rotated: conflict-free
      a2 = fmaf(w2q[j].x, v.x, a2);
      a2 = fmaf(w2q[j].y, v.y, a2);
      a2 = fmaf(w2q[j].z, v.z, a2);
      a2 = fmaf(w2q[j].w, v.w, a2);
    }
    a2 += __shfl_xor(a2, 1);
    a2 += __shfl_xor(a2, 2);
    a2 += __shfl_xor(a2, 4);
    if (q2 == 0) {
      float knew = fmaf(-LEAK_, s_y[r2], a2 + s_b2[r2]);
      kout[r2] = knew;
      if (wy) s_y[r2] = fmaf(HSTEP * GAMMA_, knew, s_pred[r2]);
    }
    __syncthreads();
  };

  // ---- stage 1 (explicit): k0 = f(y0) ----
  if (t < NXD) s_y[t] = s_y0[t];
  __syncthreads();                    // also covers s_cu
  feval(s_k[0], false);

  // ---- stages 2..7: fixed-point solve k = f(pred + h*gamma*k) ----
  for (int s = 1; s < 7; ++s) {
    if (t < NXD) {
      float p = s_y0[t];
      for (int j = 0; j < s; ++j) p = fmaf(HSTEP * c_A[s-1][j], s_k[j][t], p);
      s_pred[t] = p;
      // warm start y = pred + h*gamma*k_{s-1}
      s_y[t] = fmaf(HSTEP * GAMMA_, s_k[s-1][t], p);
    }
    __syncthreads();
    #pragma unroll 1
    for (int it = 0; it < NPIC; ++it)
      feval(s_k[s], it != NPIC - 1);
  }

  // ---- y1 = y0 + h * sum b_j k_j ----
  if (t < NXD) {
    float yv = s_y0[t];
    #pragma unroll
    for (int j = 0; j < 7; ++j) yv = fmaf(HSTEP * c_B7[j], s_k[j][t], yv);
    out[bidx * NXD + t] = yv;
  }
}

extern "C" void kernel_launch(void* const* d_in, const int* in_sizes, int n_in,
                              void* d_out, int out_size, void* d_ws, size_t ws_size,
                              hipStream_t stream) {
  const float* x  = (const float*)d_in[0];
  const float* u  = (const float*)d_in[1];
  const float* W1 = (const float*)d_in[2];
  const float* b1 = (const float*)d_in[3];
  const float* Bu = (const float*)d_in[4];
  const float* W2 = (const float*)d_in[5];
  const float* b2 = (const float*)d_in[6];
  float* out = (float*)d_out;
  const int B = in_sizes[0] / NXD;
  hipLaunchKernelGGL(kv5_kernel, dim3(B), dim3(1024), 0, stream,
                     x, u, W1, b1, Bu, W2, b2, out);
}

// Round 11
// 90.478 us; speedup vs baseline: 1.5178x; 1.0346x over previous
//
#include <hip/hip_runtime.h>
#include <math.h>

#define NXD 128
#define NHD 256
#define NUD 16
#define NPIC 2           // Picard iters/stage: rho~0.011, warm-start err<~0.3 -> k-err ~4e-5
#define HSTEP 0.02f
#define GAMMA_ 0.26f
#define LEAK_ 0.1f

// Kvaerno(5) ESDIRK tableau (lower rows, diagonal = GAMMA)
__device__ __constant__ float c_A[6][6] = {
  {0.26f, 0.f, 0.f, 0.f, 0.f, 0.f},
  {0.13f, 0.84033320996790809f, 0.f, 0.f, 0.f, 0.f},
  {0.22371961478320505f, 0.47675532319799699f, -0.06470895363112615f, 0.f, 0.f, 0.f},
  {0.16648564323248321f, 0.1045001884159172f, 0.03631482272098715f, -0.13090704451073998f, 0.f, 0.f},
  {0.13855640231268224f, 0.f, -0.04245337201752043f, 0.02446657898003141f, 0.61943039072480676f, 0.f},
  {0.13659751177640291f, 0.f, -0.05496908796538376f, -0.04118626728321046f, 0.62993304899016403f, 0.06962479448202728f},
};
__device__ __constant__ float c_B7[7] = {
  0.13659751177640291f, 0.f, -0.05496908796538376f, -0.04118626728321046f,
  0.62993304899016403f, 0.06962479448202728f, 0.26f
};

// Rounds 3/8/10 post-mortem: VGPR-resident weights are un-forceable from HIP
// source (regalloc remats/spills; 872 MB L2 traffic -> ~34us). New design:
// weights live in LDS as packed bf16 (128 KB fits; fp32's 256 KB doesn't).
// Precision: bf16 weight rounding -> k-err ~1e-2 abs, but y1 = y0 + h*sum(b*k)
// scales it by h*sum|b| ~ 0.024 -> ~2.4e-4 final, 300x under the 8e-2 bar.
// Bank plan: weight rows stride 256B/128B => slot j of every row sits on banks
// 4j..4j+3. Threads therefore READ slots in rotated order jj = j ^ rot
// (W1: rot=r1&7, W2: rot=t&7)  -- storage stays linear, the dot is
// order-invariant, and each b128 wave-instr spreads uniformly 8-per-bank-group
// (the optimum: 1024 B/instr is >=8 bank-cycles regardless).
__device__ __forceinline__ float bflo(unsigned int u) { return __uint_as_float(u << 16); }
__device__ __forceinline__ float bfhi(unsigned int u) { return __uint_as_float(u & 0xffff0000u); }
__device__ __forceinline__ unsigned int packbf(float a, float b) {
  unsigned int ua = (__float_as_uint(a) + 0x8000u) >> 16;         // RN-ish to bf16
  unsigned int ub = (__float_as_uint(b) + 0x8000u) & 0xffff0000u;
  return ua | ub;
}

__global__ __launch_bounds__(512)
void kv5_kernel(const float* __restrict__ x, const float* __restrict__ u,
                const float* __restrict__ W1g, const float* __restrict__ b1,
                const float* __restrict__ Bug, const float* __restrict__ W2g,
                const float* __restrict__ b2, float* __restrict__ out)
{
  const int bidx = blockIdx.x;
  const int t = threadIdx.x;
  const int r1 = t >> 1, c1 = t & 1;   // W1: 2 thr/row, 64-col halves
  const int r2 = t >> 2, q2 = t & 3;   // W2: 4 thr/row, 64-col quarters
  const int sw1 = r1 & 7;              // W1 slot rotation
  const int sw2 = t & 7;               // W2 slot rotation

  __shared__ uint4 s_w1[4096];         // W1 [256][128] as bf16-pairs: 64 KB
  __shared__ uint4 s_w2[4096];         // W2 [128][256] as bf16-pairs: 64 KB
  __shared__ __align__(16) float s_y[NXD];
  __shared__ __align__(16) float s_pred[NXD];
  __shared__ __align__(16) float s_y0[NXD];
  __shared__ __align__(16) float s_k[7][NXD];
  __shared__ __align__(16) float s_cu[NHD];
  __shared__ __align__(16) float s_hid[NHD];
  __shared__ __align__(16) float s_b2[NXD];
  __shared__ float s_u[NUD];

  // ---- one-time: stage weights into LDS as packed bf16 ----
  {
    unsigned int* w1u = reinterpret_cast<unsigned int*>(s_w1);
    unsigned int* w2u = reinterpret_cast<unsigned int*>(s_w2);
    const float2* g1 = reinterpret_cast<const float2*>(W1g);
    const float2* g2 = reinterpret_cast<const float2*>(W2g);
    #pragma unroll
    for (int i = 0; i < 32; ++i) {
      int idx = t + (i << 9);          // 512-thread stride, coalesced 8B/lane
      float2 a = g1[idx];
      w1u[idx] = packbf(a.x, a.y);
      float2 b = g2[idx];
      w2u[idx] = packbf(b.x, b.y);
    }
  }
  if (t < NXD) { s_y0[t] = x[bidx * NXD + t]; s_b2[t] = b2[t]; }
  if (t < NUD) { float uv = u[bidx * NUD + t]; s_u[t] = fminf(fmaxf(uv, -1.f), 1.f); }
  __syncthreads();
  if (t < NHD) {                       // cu = Bu @ clip(u) + b1 (constant for the step)
    float a = b1[t];
    #pragma unroll
    for (int j = 0; j < NUD; ++j) a = fmaf(Bug[t * NUD + j], s_u[j], a);
    s_cu[t] = a;
  }

  const uint4* w1p = s_w1 + r1 * 16 + c1 * 8;
  const uint4* w2p = s_w2 + r2 * 32 + q2 * 8;
  const float4* y4 = reinterpret_cast<const float4*>(s_y) + c1 * 16;
  const float4* h4 = reinterpret_cast<const float4*>(s_hid) + q2 * 16;

  // f(y): y in s_y -> k in kout. If WY, owner thread also writes
  // s_y[r2] = s_pred[r2] + h*gamma*k_new for the next Picard iteration.
  auto feval = [&](float* kout, bool wy) {
    float acc = 0.f;
    #pragma unroll
    for (int j = 0; j < 8; ++j) {
      int jj = j ^ sw1;                // rotated slot order: uniform bank spread
      uint4 w = w1p[jj];
      float4 ya = y4[jj * 2], yb = y4[jj * 2 + 1];
      acc = fmaf(bflo(w.x), ya.x, acc); acc = fmaf(bfhi(w.x), ya.y, acc);
      acc = fmaf(bflo(w.y), ya.z, acc); acc = fmaf(bfhi(w.y), ya.w, acc);
      acc = fmaf(bflo(w.z), yb.x, acc); acc = fmaf(bfhi(w.z), yb.y, acc);
      acc = fmaf(bflo(w.w), yb.z, acc); acc = fmaf(bfhi(w.w), yb.w, acc);
    }
    acc += __shfl_xor(acc, 1);
    if (c1 == 0) s_hid[r1] = tanhf(acc + s_cu[r1]);
    __syncthreads();
    float a2 = 0.f;
    #pragma unroll
    for (int j = 0; j < 8; ++j) {
      int jj = j ^ sw2;
      uint4 w = w2p[jj];
      float4 ha = h4[jj * 2], hb = h4[jj * 2 + 1];
      a2 = fmaf(bflo(w.x), ha.x, a2); a2 = fmaf(bfhi(w.x), ha.y, a2);
      a2 = fmaf(bflo(w.y), ha.z, a2); a2 = fmaf(bfhi(w.y), ha.w, a2);
      a2 = fmaf(bflo(w.z), hb.x, a2); a2 = fmaf(bfhi(w.z), hb.y, a2);
      a2 = fmaf(bflo(w.w), hb.z, a2); a2 = fmaf(bfhi(w.w), hb.w, a2);
    }
    a2 += __shfl_xor(a2, 1);
    a2 += __shfl_xor(a2, 2);
    if (q2 == 0) {
      float knew = fmaf(-LEAK_, s_y[r2], a2 + s_b2[r2]);
      kout[r2] = knew;
      if (wy) s_y[r2] = fmaf(HSTEP * GAMMA_, knew, s_pred[r2]);
    }
    __syncthreads();
  };

  // ---- stage 1 (explicit): k0 = f(y0) ----
  if (t < NXD) s_y[t] = s_y0[t];
  __syncthreads();                    // covers weight staging, s_cu, s_y
  feval(s_k[0], false);

  // ---- stages 2..7: fixed-point solve k = f(pred + h*gamma*k) ----
  for (int s = 1; s < 7; ++s) {
    if (t < NXD) {
      float p = s_y0[t];
      for (int j = 0; j < s; ++j) p = fmaf(HSTEP * c_A[s-1][j], s_k[j][t], p);
      s_pred[t] = p;
      // warm start y = pred + h*gamma*k_{s-1}
      s_y[t] = fmaf(HSTEP * GAMMA_, s_k[s-1][t], p);
    }
    __syncthreads();
    #pragma unroll 1
    for (int it = 0; it < NPIC; ++it)
      feval(s_k[s], it != NPIC - 1);
  }

  // ---- y1 = y0 + h * sum b_j k_j ----
  if (t < NXD) {
    float yv = s_y0[t];
    #pragma unroll
    for (int j = 0; j < 7; ++j) yv = fmaf(HSTEP * c_B7[j], s_k[j][t], yv);
    out[bidx * NXD + t] = yv;
  }
}

extern "C" void kernel_launch(void* const* d_in, const int* in_sizes, int n_in,
                              void* d_out, int out_size, void* d_ws, size_t ws_size,
                              hipStream_t stream) {
  const float* x  = (const float*)d_in[0];
  const float* u  = (const float*)d_in[1];
  const float* W1 = (const float*)d_in[2];
  const float* b1 = (const float*)d_in[3];
  const float* Bu = (const float*)d_in[4];
  const float* W2 = (const float*)d_in[5];
  const float* b2 = (const float*)d_in[6];
  float* out = (float*)d_out;
  const int B = in_sizes[0] / NXD;
  hipLaunchKernelGGL(kv5_kernel, dim3(B), dim3(512), 0, stream,
                     x, u, W1, b1, Bu, W2, b2, out);
}

// Round 12
// 83.910 us; speedup vs baseline: 1.6366x; 1.0783x over previous
//
#include <hip/hip_runtime.h>
#include <math.h>

#define NXD 128
#define NHD 256
#define NUD 16
#define HSTEP 0.02f
#define GAMMA_ 0.26f
#define LEAK_ 0.1f

// Kvaerno(5) ESDIRK tableau. cA row s = predictor coefficients for stage s+1
// (A_LOWER[s] in the reference); constexpr + full unroll -> immediates.
__device__ constexpr float cA[6][6] = {
  {0.26f, 0.f, 0.f, 0.f, 0.f, 0.f},
  {0.13f, 0.84033320996790809f, 0.f, 0.f, 0.f, 0.f},
  {0.22371961478320505f, 0.47675532319799699f, -0.06470895363112615f, 0.f, 0.f, 0.f},
  {0.16648564323248321f, 0.1045001884159172f, 0.03631482272098715f, -0.13090704451073998f, 0.f, 0.f},
  {0.13855640231268224f, 0.f, -0.04245337201752043f, 0.02446657898003141f, 0.61943039072480676f, 0.f},
  {0.13659751177640291f, 0.f, -0.05496908796538376f, -0.04118626728321046f, 0.62993304899016403f, 0.06962479448202728f},
};
__device__ constexpr float cB[7] = {
  0.13659751177640291f, 0.f, -0.05496908796538376f, -0.04118626728321046f,
  0.62993304899016403f, 0.06962479448202728f, 0.26f
};

// Round-11 post-mortem: LDS instr pipe is the binding resource (384 b128/CU/eval
// x ~12cyc = 25us). Fix: swizzle WEIGHT STORAGE (slot j stored at j^(row&7)),
// so weight reads keep the b128 unique-data floor while y/hid reads stay
// wave-uniform -> LDS broadcast (~2-4cyc). Plus NPIC=1 (7 evals) and the
// stage predictor folded into the k-write phase: 14 barrier-phases total.
__device__ __forceinline__ float bflo(unsigned int u) { return __uint_as_float(u << 16); }
__device__ __forceinline__ float bfhi(unsigned int u) { return __uint_as_float(u & 0xffff0000u); }
__device__ __forceinline__ unsigned int packbf(float a, float b) {
  unsigned int ua = (__float_as_uint(a) + 0x8000u) >> 16;
  unsigned int ub = (__float_as_uint(b) + 0x8000u) & 0xffff0000u;
  return ua | ub;
}

__global__ __launch_bounds__(512)
void kv5_kernel(const float* __restrict__ x, const float* __restrict__ u,
                const float* __restrict__ W1g, const float* __restrict__ b1,
                const float* __restrict__ Bug, const float* __restrict__ W2g,
                const float* __restrict__ b2, float* __restrict__ out)
{
  const int bidx = blockIdx.x;
  const int t = threadIdx.x;
  const int r1 = t >> 1, c1 = t & 1;   // W1: 2 thr/row, 64-col halves
  const int r2 = t >> 2, q2 = t & 3;   // W2: 4 thr/row, 64-col quarters
  const int sw1 = r1 & 7;              // storage rotation keys
  const int sw2 = r2 & 7;

  __shared__ uint4 s_w1[4096];         // W1 [256][128] bf16-pairs, slot-swizzled: 64 KB
  __shared__ uint4 s_w2[4096];         // W2 [128][256] bf16-pairs, slot-swizzled: 64 KB
  __shared__ __align__(16) float s_y[NXD];
  __shared__ __align__(16) float s_y0[NXD];
  __shared__ __align__(16) float s_k[7][NXD];
  __shared__ __align__(16) float s_cu[NHD];
  __shared__ __align__(16) float s_hid[NHD];
  __shared__ __align__(16) float s_b2[NXD];
  __shared__ float s_u[NUD];

  // ---- one-time: stage weights into LDS as packed bf16, slot-swizzled ----
  // W1 uint layout: uidx = r1*64 + c1*32 + slot*4 + e  -> slot ^= (r1&7) = bits[8:6]
  // W2 uint layout: uidx = r2*128 + q2*32 + slot*4 + e -> slot ^= (r2&7) = bits[9:7]
  {
    unsigned int* w1u = reinterpret_cast<unsigned int*>(s_w1);
    unsigned int* w2u = reinterpret_cast<unsigned int*>(s_w2);
    const float2* g1 = reinterpret_cast<const float2*>(W1g);
    const float2* g2 = reinterpret_cast<const float2*>(W2g);
    #pragma unroll
    for (int i = 0; i < 32; ++i) {
      int idx = t + (i << 9);          // coalesced 8B/lane
      float2 a = g1[idx];
      w1u[idx ^ (((idx >> 6) & 7) << 2)] = packbf(a.x, a.y);
      float2 b = g2[idx];
      w2u[idx ^ (((idx >> 7) & 7) << 2)] = packbf(b.x, b.y);
    }
  }
  if (t < NXD) { s_y0[t] = x[bidx * NXD + t]; s_b2[t] = b2[t]; }
  if (t < NUD) { float uv = u[bidx * NUD + t]; s_u[t] = fminf(fmaxf(uv, -1.f), 1.f); }
  __syncthreads();
  if (t < NHD) {                       // cu = Bu @ clip(u) + b1 (constant for the step)
    float a = b1[t];
    #pragma unroll
    for (int j = 0; j < NUD; ++j) a = fmaf(Bug[t * NUD + j], s_u[j], a);
    s_cu[t] = a;
  }
  if (t < NXD) s_y[t] = s_y0[t];       // stage-0 input

  const uint4* w1p = s_w1 + r1 * 16 + c1 * 8;
  const uint4* w2p = s_w2 + r2 * 32 + q2 * 8;
  const float4* y4 = reinterpret_cast<const float4*>(s_y) + c1 * 16;
  const float4* h4 = reinterpret_cast<const float4*>(s_hid) + q2 * 16;

  __syncthreads();                     // weights + s_cu + s_y ready

  // ---- 7 stages, 1 f-eval each (Picard-1 from warm start k_{s-1}) ----
  #pragma unroll
  for (int s = 0; s < 7; ++s) {
    // phase 1: hid = tanh(W1 @ y + cu)
    float acc = 0.f;
    #pragma unroll
    for (int j = 0; j < 8; ++j) {
      uint4 w = w1p[j ^ sw1];          // swizzled storage -> conflict-floor reads
      float4 ya = y4[2 * j], yb = y4[2 * j + 1];   // wave-uniform -> broadcast
      acc = fmaf(bflo(w.x), ya.x, acc); acc = fmaf(bfhi(w.x), ya.y, acc);
      acc = fmaf(bflo(w.y), ya.z, acc); acc = fmaf(bfhi(w.y), ya.w, acc);
      acc = fmaf(bflo(w.z), yb.x, acc); acc = fmaf(bfhi(w.z), yb.y, acc);
      acc = fmaf(bflo(w.w), yb.z, acc); acc = fmaf(bfhi(w.w), yb.w, acc);
    }
    acc += __shfl_xor(acc, 1);
    if (c1 == 0) s_hid[r1] = tanhf(acc + s_cu[r1]);
    __syncthreads();
    // phase 2: k_s = -leak*y + W2 @ hid + b2 ; owner also writes next-stage y
    float a2 = 0.f;
    #pragma unroll
    for (int j = 0; j < 8; ++j) {
      uint4 w = w2p[j ^ sw2];
      float4 ha = h4[2 * j], hb = h4[2 * j + 1];
      a2 = fmaf(bflo(w.x), ha.x, a2); a2 = fmaf(bfhi(w.x), ha.y, a2);
      a2 = fmaf(bflo(w.y), ha.z, a2); a2 = fmaf(bfhi(w.y), ha.w, a2);
      a2 = fmaf(bflo(w.z), hb.x, a2); a2 = fmaf(bfhi(w.z), hb.y, a2);
      a2 = fmaf(bflo(w.w), hb.z, a2); a2 = fmaf(bfhi(w.w), hb.w, a2);
    }
    a2 += __shfl_xor(a2, 1);
    a2 += __shfl_xor(a2, 2);
    if (q2 == 0) {
      float knew = fmaf(-LEAK_, s_y[r2], a2 + s_b2[r2]);
      s_k[s][r2] = knew;
      if (s < 6) {                     // next-stage warm start:
        float p = s_y0[r2];            // y = y0 + h*sum(a[s][j]*k_j) + h*gamma*k_s
        #pragma unroll
        for (int j = 0; j < s; ++j) p = fmaf(HSTEP * cA[s][j], s_k[j][r2], p);
        p = fmaf(HSTEP * cA[s][s], knew, p);
        s_y[r2] = fmaf(HSTEP * GAMMA_, knew, p);
      }
    }
    __syncthreads();
  }

  // ---- y1 = y0 + h * sum b_j k_j ----
  if (t < NXD) {
    float yv = s_y0[t];
    #pragma unroll
    for (int j = 0; j < 7; ++j) yv = fmaf(HSTEP * cB[j], s_k[j][t], yv);
    out[bidx * NXD + t] = yv;
  }
}

extern "C" void kernel_launch(void* const* d_in, const int* in_sizes, int n_in,
                              void* d_out, int out_size, void* d_ws, size_t ws_size,
                              hipStream_t stream) {
  const float* x  = (const float*)d_in[0];
  const float* u  = (const float*)d_in[1];
  const float* W1 = (const float*)d_in[2];
  const float* b1 = (const float*)d_in[3];
  const float* Bu = (const float*)d_in[4];
  const float* W2 = (const float*)d_in[5];
  const float* b2 = (const float*)d_in[6];
  float* out = (float*)d_out;
  const int B = in_sizes[0] / NXD;
  hipLaunchKernelGGL(kv5_kernel, dim3(B), dim3(512), 0, stream,
                     x, u, W1, b1, Bu, W2, b2, out);
}